// Round 3
// baseline (358.490 us; speedup 1.0000x reference)
//
#include <hip/hip_runtime.h>

// DeepFM fused ranker, fp32.
// R7: occupancy fix. R6 counters showed the real limiter: 2 blocks/CU
// (grid 512), Occupancy 22%, VALUBusy 11%, HBM 0.6% -> pure latency-bound.
//  - ROWS_PER_BLOCK 32 -> 16, grid 1024 -> 4 blocks/CU, 16 waves/CU.
//  - Phases B/C revert to the proven R4 tilings (2 neurons/lane, jp-16 groups,
//    wave-coalesced contiguous weight stream), at half rows per lane.
//  - LDS 13.4 KB/block, acc halves -> ~80 VGPR; __launch_bounds__(256,4).

typedef float v2f __attribute__((ext_vector_type(2)));
static __device__ __forceinline__ v2f bc2(float x) { v2f r; r.x = x; r.y = x; return r; }
static __device__ __forceinline__ float relu1(float x) { return fmaxf(x, 0.f); }

#define ROWS_PER_BLOCK 16
#define ROWS_PER_WAVE 4
#define DI_STRIDE 204            // floats; 51 float4
#define H1_STRIDE 132            // floats; 33 float4

// ---- pre-pass: pair-transposed packed weights (R4 layout) ----
// W1p[((wid*50+k4)*16+jp)*2+s] = {W1[j0][c],W1[j1][c],W1[j0][c+1],W1[j1][c+1]}
//   j0 = 32*wid + 2*jp, c = 4*k4 + 2*s
// W2p[((wid*32+k4)*8+jp)*2+s]  = same with j0 = 16*wid + 2*jp, row len 128
__global__ void pack_weights(const float* __restrict__ W1, const float* __restrict__ W2,
                             float4* __restrict__ W1p, float4* __restrict__ W2p) {
    const int idx = blockIdx.x * blockDim.x + threadIdx.x;
    if (idx < 6400) {
        const int s = idx & 1, jp = (idx >> 1) & 15, k4 = (idx >> 5) % 50, w = idx / 1600;
        const int j0 = w * 32 + 2 * jp, c = 4 * k4 + 2 * s;
        W1p[idx] = make_float4(W1[j0 * 200 + c],     W1[(j0 + 1) * 200 + c],
                               W1[j0 * 200 + c + 1], W1[(j0 + 1) * 200 + c + 1]);
    }
    if (idx < 2048) {
        const int s = idx & 1, jp = (idx >> 1) & 7, k4 = (idx >> 4) & 31, w = idx >> 9;
        const int j0 = w * 16 + 2 * jp, c = 4 * k4 + 2 * s;
        W2p[idx] = make_float4(W2[j0 * 128 + c],     W2[(j0 + 1) * 128 + c],
                               W2[j0 * 128 + c + 1], W2[(j0 + 1) * 128 + c + 1]);
    }
}

__global__ __launch_bounds__(256, 4) void deepfm_kernel(
    const int* __restrict__ user_id, const int* __restrict__ item_id,
    const int* __restrict__ gender_, const int* __restrict__ age_,
    const int* __restrict__ occ_, const int* __restrict__ genre_ids,
    const float* __restrict__ genre_mask, const float* __restrict__ dense,
    const float* __restrict__ fo_user, const float* __restrict__ fo_item,
    const float* __restrict__ fo_gender, const float* __restrict__ fo_age,
    const float* __restrict__ fo_occ, const float* __restrict__ fo_genre,
    const float* __restrict__ emb_user, const float* __restrict__ emb_item,
    const float* __restrict__ emb_gender, const float* __restrict__ emb_age,
    const float* __restrict__ emb_occ, const float* __restrict__ emb_genre,
    const float* __restrict__ dense_W, const float* __restrict__ dense_b,
    const float4* __restrict__ W1p, const float* __restrict__ b1,
    const float4* __restrict__ W2p, const float* __restrict__ b2,
    const float* __restrict__ Wout, const float* __restrict__ bout,
    float* __restrict__ out, int B)
{
    __shared__ float lds_di[ROWS_PER_BLOCK][DI_STRIDE];   // 13.1 KB; h1[16][132] overlays
    __shared__ float lds_rs[ROWS_PER_BLOCK];
    __shared__ float lds_part[ROWS_PER_BLOCK][4];

    const int tid = threadIdx.x;
    const int wid = tid >> 6;
    const int lane = tid & 63;
    const int blockRow0 = blockIdx.x * ROWS_PER_BLOCK;

    // ---------------- Phase A: gather + FM first/second order (wave owns 4 rows) ----
    {
        const int rowBase = blockRow0 + wid * ROWS_PER_WAVE;
        int uid[ROWS_PER_WAVE], iid[ROWS_PER_WAVE], gg[ROWS_PER_WAVE],
            aa[ROWS_PER_WAVE], oo[ROWS_PER_WAVE];
        #pragma unroll
        for (int r = 0; r < ROWS_PER_WAVE; ++r) {
            int row = rowBase + r; if (row >= B) row = B - 1;
            uid[r] = user_id[row]; iid[r] = item_id[row];
            gg[r] = gender_[row];  aa[r] = age_[row];  oo[r] = occ_[row];
        }

        #pragma unroll
        for (int r = 0; r < ROWS_PER_WAVE; ++r) {
            int row = rowBase + r; if (row >= B) row = B - 1;
            const int ri = wid * ROWS_PER_WAVE + r;

            int gid[6]; float mk[6]; float msum = 0.f;
            #pragma unroll
            for (int t = 0; t < 6; ++t) {
                gid[t] = genre_ids[row * 6 + t];
                mk[t]  = genre_mask[row * 6 + t];
                msum  += mk[t];
            }
            const float inv_den = 1.0f / fmaxf(msum, 1.0f);

            float pe_sum = 0.f, pe_sq = 0.f;
            {
                float v = (lane < 32) ? emb_user[(size_t)uid[r] * 32 + lane]
                                      : emb_item[(size_t)iid[r] * 32 + (lane - 32)];
                lds_di[ri][lane] = v;
                pe_sum += v; pe_sq += v * v;
            }
            {
                float v = (lane < 32) ? emb_gender[gg[r] * 32 + lane]
                                      : emb_age[aa[r] * 32 + (lane - 32)];
                lds_di[ri][64 + lane] = v;
                pe_sum += v; pe_sq += v * v;
            }
            {
                float v;
                if (lane < 32) {
                    v = emb_occ[oo[r] * 32 + lane];
                } else {
                    const int d = lane - 32;
                    float s = 0.f;
                    #pragma unroll
                    for (int t = 0; t < 6; ++t) s += mk[t] * emb_genre[gid[t] * 32 + d];
                    v = s * inv_den;
                }
                lds_di[ri][128 + lane] = v;
                pe_sum += v; pe_sq += v * v;
            }
            if (lane < 8) lds_di[ri][192 + lane] = dense[(size_t)row * 8 + lane];

            float s2 = pe_sum + __shfl_xor(pe_sum, 32);
            float ss = pe_sq  + __shfl_xor(pe_sq, 32);
            float t2 = 0.5f * (s2 * s2 - ss);
            #pragma unroll
            for (int off = 16; off >= 1; off >>= 1) t2 += __shfl_xor(t2, off);

            float fo = fo_user[uid[r]] + fo_item[iid[r]] + fo_gender[gg[r]]
                     + fo_age[aa[r]] + fo_occ[oo[r]];
            float fg = 0.f;
            #pragma unroll
            for (int t = 0; t < 6; ++t) fg += mk[t] * fo_genre[gid[t]];
            fo += fg * inv_den;
            float dd = 0.f;
            #pragma unroll
            for (int j = 0; j < 8; ++j) dd += dense[(size_t)row * 8 + j] * dense_W[j];
            fo += dd + dense_b[0];

            if (lane == 0) lds_rs[ri] = fo + t2;
        }
    }
    __syncthreads();

    // ---------------- Phase B: h1 = relu(deep_in @ W1^T + b1) ----------------------
    // wave owns neurons [32*wid, 32*wid+32); lane: jp1=lane&15 -> pair {2jp,2jp+1},
    // rh=lane>>4 -> rows {rh+4r}, r=0..3. Per k4: 4 act b128 (4 distinct rows,
    // conflict-free) + 2 weight b128 (wave-coalesced contiguous) + 16 v_pk_fma.
    const int jp1 = lane & 15;
    const int rh  = lane >> 4;

    v2f acc[ROWS_PER_WAVE];
    #pragma unroll
    for (int r = 0; r < ROWS_PER_WAVE; ++r) acc[r] = bc2(0.f);

    {
        const float4* __restrict__ W1b = W1p + wid * 1600;
        const float4* __restrict__ dv = reinterpret_cast<const float4*>(&lds_di[0][0]); // stride 51

        for (int k4 = 0; k4 < 50; ++k4) {
            const float4 wa = W1b[(k4 * 16 + jp1) * 2 + 0];   // {j0k0,j1k0,j0k1,j1k1}
            const float4 wb = W1b[(k4 * 16 + jp1) * 2 + 1];   // {j0k2,j1k2,j0k3,j1k3}
            const v2f w0 = { wa.x, wa.y }, w1 = { wa.z, wa.w };
            const v2f w2 = { wb.x, wb.y }, w3 = { wb.z, wb.w };
            #pragma unroll
            for (int r = 0; r < ROWS_PER_WAVE; ++r) {
                const float4 a = dv[(rh + 4 * r) * 51 + k4];
                acc[r] = __builtin_elementwise_fma(w0, bc2(a.x), acc[r]);
                acc[r] = __builtin_elementwise_fma(w1, bc2(a.y), acc[r]);
                acc[r] = __builtin_elementwise_fma(w2, bc2(a.z), acc[r]);
                acc[r] = __builtin_elementwise_fma(w3, bc2(a.w), acc[r]);
            }
        }
    }
    __syncthreads();   // all deep_in reads done; overlay h1

    float* __restrict__ h1b = &lds_di[0][0];   // h1[row][j] at row*132 + j
    {
        const int j0 = wid * 32 + 2 * jp1;
        const float2 bb = *reinterpret_cast<const float2*>(b1 + j0);
        #pragma unroll
        for (int r = 0; r < ROWS_PER_WAVE; ++r) {
            const int row = rh + 4 * r;
            reinterpret_cast<float2*>(h1b)[(row * H1_STRIDE + j0) >> 1] =
                make_float2(relu1(acc[r].x + bb.x), relu1(acc[r].y + bb.y));
        }
    }
    __syncthreads();

    // ---------------- Phase C: h2 = relu(h1 @ W2^T + b2) ---------------------------
    // wave owns neurons [16*wid,16*wid+16); lane: jp2=lane&7 -> pair, rh2=lane>>3 ->
    // rows {rh2+8t}, t=0..1. Conflict-free via stride 132.
    const int jp2 = lane & 7;
    const int rh2 = lane >> 3;

    v2f acc2[2];
    acc2[0] = bc2(0.f); acc2[1] = bc2(0.f);

    {
        const float4* __restrict__ W2b = W2p + wid * 512;
        const float4* __restrict__ h1v = reinterpret_cast<const float4*>(h1b); // stride 33

        for (int k4 = 0; k4 < 32; ++k4) {
            const float4 wa = W2b[(k4 * 8 + jp2) * 2 + 0];
            const float4 wb = W2b[(k4 * 8 + jp2) * 2 + 1];
            const v2f w0 = { wa.x, wa.y }, w1 = { wa.z, wa.w };
            const v2f w2 = { wb.x, wb.y }, w3 = { wb.z, wb.w };
            #pragma unroll
            for (int t = 0; t < 2; ++t) {
                const float4 h = h1v[(rh2 + 8 * t) * 33 + k4];
                acc2[t] = __builtin_elementwise_fma(w0, bc2(h.x), acc2[t]);
                acc2[t] = __builtin_elementwise_fma(w1, bc2(h.y), acc2[t]);
                acc2[t] = __builtin_elementwise_fma(w2, bc2(h.z), acc2[t]);
                acc2[t] = __builtin_elementwise_fma(w3, bc2(h.w), acc2[t]);
            }
        }
    }

    // ---------------- Phase D: Wout dot + combine ----------------------------------
    {
        const int j0 = wid * 16 + 2 * jp2;
        const float2 bb2 = *reinterpret_cast<const float2*>(b2 + j0);
        const float2 wo  = *reinterpret_cast<const float2*>(Wout + j0);
        #pragma unroll
        for (int t = 0; t < 2; ++t) {
            const float h2x = relu1(acc2[t].x + bb2.x);
            const float h2y = relu1(acc2[t].y + bb2.y);
            float v = wo.x * h2x + wo.y * h2y;
            v += __shfl_xor(v, 1); v += __shfl_xor(v, 2); v += __shfl_xor(v, 4);
            if (jp2 == 0) lds_part[rh2 + 8 * t][wid] = v;
        }
    }
    __syncthreads();

    if (tid < ROWS_PER_BLOCK) {
        const int row = blockRow0 + tid;
        if (row < B) {
            const float deep = lds_part[tid][0] + lds_part[tid][1]
                             + lds_part[tid][2] + lds_part[tid][3] + bout[0];
            out[row] = deep + lds_rs[tid];
        }
    }
}

extern "C" void kernel_launch(void* const* d_in, const int* in_sizes, int n_in,
                              void* d_out, int out_size, void* d_ws, size_t ws_size,
                              hipStream_t stream) {
    const int B = in_sizes[0];

    float4* W1p = reinterpret_cast<float4*>(d_ws);                  // 6400 float4 = 100 KB
    float4* W2p = reinterpret_cast<float4*>((char*)d_ws + 102400);  // 2048 float4 = 32 KB

    pack_weights<<<25, 256, 0, stream>>>(
        (const float*)d_in[22], (const float*)d_in[24], W1p, W2p);

    const int grid = (B + ROWS_PER_BLOCK - 1) / ROWS_PER_BLOCK;  // 1024 at B=16384
    deepfm_kernel<<<grid, 256, 0, stream>>>(
        (const int*)d_in[0],  (const int*)d_in[1],  (const int*)d_in[2],
        (const int*)d_in[3],  (const int*)d_in[4],  (const int*)d_in[5],
        (const float*)d_in[6],  (const float*)d_in[7],
        (const float*)d_in[8],  (const float*)d_in[9],  (const float*)d_in[10],
        (const float*)d_in[11], (const float*)d_in[12], (const float*)d_in[13],
        (const float*)d_in[14], (const float*)d_in[15], (const float*)d_in[16],
        (const float*)d_in[17], (const float*)d_in[18], (const float*)d_in[19],
        (const float*)d_in[20], (const float*)d_in[21],
        W1p, (const float*)d_in[23],
        W2p, (const float*)d_in[25],
        (const float*)d_in[26], (const float*)d_in[27],
        (float*)d_out, B);
}

// Round 4
// 296.124 us; speedup vs baseline: 1.2106x; 1.2106x over previous
//
#include <hip/hip_runtime.h>

// DeepFM fused ranker, fp32.
// R8: R7 minus the spill bomb. R7's __launch_bounds__(256,4) clamped VGPR to 64
// and spilled phase-A arrays to scratch: WRITE_SIZE 278 MB / FETCH 146 MB of
// pure scratch traffic = the whole 166 us. Keep the occupancy win (ROWS 16,
// grid 1024 -> 4 blocks/CU, measured Occupancy 38%) and R4's proven inner
// tilings; let the allocator have its ~80 VGPRs.

typedef float v2f __attribute__((ext_vector_type(2)));
static __device__ __forceinline__ v2f bc2(float x) { v2f r; r.x = x; r.y = x; return r; }
static __device__ __forceinline__ float relu1(float x) { return fmaxf(x, 0.f); }

#define ROWS_PER_BLOCK 16
#define ROWS_PER_WAVE 4
#define DI_STRIDE 204            // floats; 51 float4
#define H1_STRIDE 132            // floats; 33 float4

// ---- pre-pass: pair-transposed packed weights (R4 layout) ----
// W1p[((wid*50+k4)*16+jp)*2+s] = {W1[j0][c],W1[j1][c],W1[j0][c+1],W1[j1][c+1]}
//   j0 = 32*wid + 2*jp, c = 4*k4 + 2*s
// W2p[((wid*32+k4)*8+jp)*2+s]  = same with j0 = 16*wid + 2*jp, row len 128
__global__ void pack_weights(const float* __restrict__ W1, const float* __restrict__ W2,
                             float4* __restrict__ W1p, float4* __restrict__ W2p) {
    const int idx = blockIdx.x * blockDim.x + threadIdx.x;
    if (idx < 6400) {
        const int s = idx & 1, jp = (idx >> 1) & 15, k4 = (idx >> 5) % 50, w = idx / 1600;
        const int j0 = w * 32 + 2 * jp, c = 4 * k4 + 2 * s;
        W1p[idx] = make_float4(W1[j0 * 200 + c],     W1[(j0 + 1) * 200 + c],
                               W1[j0 * 200 + c + 1], W1[(j0 + 1) * 200 + c + 1]);
    }
    if (idx < 2048) {
        const int s = idx & 1, jp = (idx >> 1) & 7, k4 = (idx >> 4) & 31, w = idx >> 9;
        const int j0 = w * 16 + 2 * jp, c = 4 * k4 + 2 * s;
        W2p[idx] = make_float4(W2[j0 * 128 + c],     W2[(j0 + 1) * 128 + c],
                               W2[j0 * 128 + c + 1], W2[(j0 + 1) * 128 + c + 1]);
    }
}

__global__ __launch_bounds__(256) void deepfm_kernel(
    const int* __restrict__ user_id, const int* __restrict__ item_id,
    const int* __restrict__ gender_, const int* __restrict__ age_,
    const int* __restrict__ occ_, const int* __restrict__ genre_ids,
    const float* __restrict__ genre_mask, const float* __restrict__ dense,
    const float* __restrict__ fo_user, const float* __restrict__ fo_item,
    const float* __restrict__ fo_gender, const float* __restrict__ fo_age,
    const float* __restrict__ fo_occ, const float* __restrict__ fo_genre,
    const float* __restrict__ emb_user, const float* __restrict__ emb_item,
    const float* __restrict__ emb_gender, const float* __restrict__ emb_age,
    const float* __restrict__ emb_occ, const float* __restrict__ emb_genre,
    const float* __restrict__ dense_W, const float* __restrict__ dense_b,
    const float4* __restrict__ W1p, const float* __restrict__ b1,
    const float4* __restrict__ W2p, const float* __restrict__ b2,
    const float* __restrict__ Wout, const float* __restrict__ bout,
    float* __restrict__ out, int B)
{
    __shared__ float lds_di[ROWS_PER_BLOCK][DI_STRIDE];   // 13.1 KB; h1[16][132] overlays
    __shared__ float lds_rs[ROWS_PER_BLOCK];
    __shared__ float lds_part[ROWS_PER_BLOCK][4];

    const int tid = threadIdx.x;
    const int wid = tid >> 6;
    const int lane = tid & 63;
    const int blockRow0 = blockIdx.x * ROWS_PER_BLOCK;

    // ---------------- Phase A: gather + FM first/second order (wave owns 4 rows) ----
    {
        const int rowBase = blockRow0 + wid * ROWS_PER_WAVE;
        int uid[ROWS_PER_WAVE], iid[ROWS_PER_WAVE], gg[ROWS_PER_WAVE],
            aa[ROWS_PER_WAVE], oo[ROWS_PER_WAVE];
        #pragma unroll
        for (int r = 0; r < ROWS_PER_WAVE; ++r) {
            int row = rowBase + r; if (row >= B) row = B - 1;
            uid[r] = user_id[row]; iid[r] = item_id[row];
            gg[r] = gender_[row];  aa[r] = age_[row];  oo[r] = occ_[row];
        }

        #pragma unroll
        for (int r = 0; r < ROWS_PER_WAVE; ++r) {
            int row = rowBase + r; if (row >= B) row = B - 1;
            const int ri = wid * ROWS_PER_WAVE + r;

            int gid[6]; float mk[6]; float msum = 0.f;
            #pragma unroll
            for (int t = 0; t < 6; ++t) {
                gid[t] = genre_ids[row * 6 + t];
                mk[t]  = genre_mask[row * 6 + t];
                msum  += mk[t];
            }
            const float inv_den = 1.0f / fmaxf(msum, 1.0f);

            float pe_sum = 0.f, pe_sq = 0.f;
            {
                float v = (lane < 32) ? emb_user[(size_t)uid[r] * 32 + lane]
                                      : emb_item[(size_t)iid[r] * 32 + (lane - 32)];
                lds_di[ri][lane] = v;
                pe_sum += v; pe_sq += v * v;
            }
            {
                float v = (lane < 32) ? emb_gender[gg[r] * 32 + lane]
                                      : emb_age[aa[r] * 32 + (lane - 32)];
                lds_di[ri][64 + lane] = v;
                pe_sum += v; pe_sq += v * v;
            }
            {
                float v;
                if (lane < 32) {
                    v = emb_occ[oo[r] * 32 + lane];
                } else {
                    const int d = lane - 32;
                    float s = 0.f;
                    #pragma unroll
                    for (int t = 0; t < 6; ++t) s += mk[t] * emb_genre[gid[t] * 32 + d];
                    v = s * inv_den;
                }
                lds_di[ri][128 + lane] = v;
                pe_sum += v; pe_sq += v * v;
            }
            if (lane < 8) lds_di[ri][192 + lane] = dense[(size_t)row * 8 + lane];

            float s2 = pe_sum + __shfl_xor(pe_sum, 32);
            float ss = pe_sq  + __shfl_xor(pe_sq, 32);
            float t2 = 0.5f * (s2 * s2 - ss);
            #pragma unroll
            for (int off = 16; off >= 1; off >>= 1) t2 += __shfl_xor(t2, off);

            float fo = fo_user[uid[r]] + fo_item[iid[r]] + fo_gender[gg[r]]
                     + fo_age[aa[r]] + fo_occ[oo[r]];
            float fg = 0.f;
            #pragma unroll
            for (int t = 0; t < 6; ++t) fg += mk[t] * fo_genre[gid[t]];
            fo += fg * inv_den;
            float dd = 0.f;
            #pragma unroll
            for (int j = 0; j < 8; ++j) dd += dense[(size_t)row * 8 + j] * dense_W[j];
            fo += dd + dense_b[0];

            if (lane == 0) lds_rs[ri] = fo + t2;
        }
    }
    __syncthreads();

    // ---------------- Phase B: h1 = relu(deep_in @ W1^T + b1) ----------------------
    // wave owns neurons [32*wid, 32*wid+32); lane: jp1=lane&15 -> pair {2jp,2jp+1},
    // rh=lane>>4 -> rows {rh+4r}, r=0..3. Per k4: 4 act b128 (4 distinct rows,
    // conflict-free) + 2 weight b128 (wave-coalesced contiguous) + 16 v_pk_fma.
    const int jp1 = lane & 15;
    const int rh  = lane >> 4;

    v2f acc[ROWS_PER_WAVE];
    #pragma unroll
    for (int r = 0; r < ROWS_PER_WAVE; ++r) acc[r] = bc2(0.f);

    {
        const float4* __restrict__ W1b = W1p + wid * 1600;
        const float4* __restrict__ dv = reinterpret_cast<const float4*>(&lds_di[0][0]); // stride 51

        for (int k4 = 0; k4 < 50; ++k4) {
            const float4 wa = W1b[(k4 * 16 + jp1) * 2 + 0];   // {j0k0,j1k0,j0k1,j1k1}
            const float4 wb = W1b[(k4 * 16 + jp1) * 2 + 1];   // {j0k2,j1k2,j0k3,j1k3}
            const v2f w0 = { wa.x, wa.y }, w1 = { wa.z, wa.w };
            const v2f w2 = { wb.x, wb.y }, w3 = { wb.z, wb.w };
            #pragma unroll
            for (int r = 0; r < ROWS_PER_WAVE; ++r) {
                const float4 a = dv[(rh + 4 * r) * 51 + k4];
                acc[r] = __builtin_elementwise_fma(w0, bc2(a.x), acc[r]);
                acc[r] = __builtin_elementwise_fma(w1, bc2(a.y), acc[r]);
                acc[r] = __builtin_elementwise_fma(w2, bc2(a.z), acc[r]);
                acc[r] = __builtin_elementwise_fma(w3, bc2(a.w), acc[r]);
            }
        }
    }
    __syncthreads();   // all deep_in reads done; overlay h1

    float* __restrict__ h1b = &lds_di[0][0];   // h1[row][j] at row*132 + j
    {
        const int j0 = wid * 32 + 2 * jp1;
        const float2 bb = *reinterpret_cast<const float2*>(b1 + j0);
        #pragma unroll
        for (int r = 0; r < ROWS_PER_WAVE; ++r) {
            const int row = rh + 4 * r;
            reinterpret_cast<float2*>(h1b)[(row * H1_STRIDE + j0) >> 1] =
                make_float2(relu1(acc[r].x + bb.x), relu1(acc[r].y + bb.y));
        }
    }
    __syncthreads();

    // ---------------- Phase C: h2 = relu(h1 @ W2^T + b2) ---------------------------
    // wave owns neurons [16*wid,16*wid+16); lane: jp2=lane&7 -> pair, rh2=lane>>3 ->
    // rows {rh2+8t}, t=0..1. Conflict-free via stride 132.
    const int jp2 = lane & 7;
    const int rh2 = lane >> 3;

    v2f acc2[2];
    acc2[0] = bc2(0.f); acc2[1] = bc2(0.f);

    {
        const float4* __restrict__ W2b = W2p + wid * 512;
        const float4* __restrict__ h1v = reinterpret_cast<const float4*>(h1b); // stride 33

        for (int k4 = 0; k4 < 32; ++k4) {
            const float4 wa = W2b[(k4 * 8 + jp2) * 2 + 0];
            const float4 wb = W2b[(k4 * 8 + jp2) * 2 + 1];
            const v2f w0 = { wa.x, wa.y }, w1 = { wa.z, wa.w };
            const v2f w2 = { wb.x, wb.y }, w3 = { wb.z, wb.w };
            #pragma unroll
            for (int t = 0; t < 2; ++t) {
                const float4 h = h1v[(rh2 + 8 * t) * 33 + k4];
                acc2[t] = __builtin_elementwise_fma(w0, bc2(h.x), acc2[t]);
                acc2[t] = __builtin_elementwise_fma(w1, bc2(h.y), acc2[t]);
                acc2[t] = __builtin_elementwise_fma(w2, bc2(h.z), acc2[t]);
                acc2[t] = __builtin_elementwise_fma(w3, bc2(h.w), acc2[t]);
            }
        }
    }

    // ---------------- Phase D: Wout dot + combine ----------------------------------
    {
        const int j0 = wid * 16 + 2 * jp2;
        const float2 bb2 = *reinterpret_cast<const float2*>(b2 + j0);
        const float2 wo  = *reinterpret_cast<const float2*>(Wout + j0);
        #pragma unroll
        for (int t = 0; t < 2; ++t) {
            const float h2x = relu1(acc2[t].x + bb2.x);
            const float h2y = relu1(acc2[t].y + bb2.y);
            float v = wo.x * h2x + wo.y * h2y;
            v += __shfl_xor(v, 1); v += __shfl_xor(v, 2); v += __shfl_xor(v, 4);
            if (jp2 == 0) lds_part[rh2 + 8 * t][wid] = v;
        }
    }
    __syncthreads();

    if (tid < ROWS_PER_BLOCK) {
        const int row = blockRow0 + tid;
        if (row < B) {
            const float deep = lds_part[tid][0] + lds_part[tid][1]
                             + lds_part[tid][2] + lds_part[tid][3] + bout[0];
            out[row] = deep + lds_rs[tid];
        }
    }
}

extern "C" void kernel_launch(void* const* d_in, const int* in_sizes, int n_in,
                              void* d_out, int out_size, void* d_ws, size_t ws_size,
                              hipStream_t stream) {
    const int B = in_sizes[0];

    float4* W1p = reinterpret_cast<float4*>(d_ws);                  // 6400 float4 = 100 KB
    float4* W2p = reinterpret_cast<float4*>((char*)d_ws + 102400);  // 2048 float4 = 32 KB

    pack_weights<<<25, 256, 0, stream>>>(
        (const float*)d_in[22], (const float*)d_in[24], W1p, W2p);

    const int grid = (B + ROWS_PER_BLOCK - 1) / ROWS_PER_BLOCK;  // 1024 at B=16384
    deepfm_kernel<<<grid, 256, 0, stream>>>(
        (const int*)d_in[0],  (const int*)d_in[1],  (const int*)d_in[2],
        (const int*)d_in[3],  (const int*)d_in[4],  (const int*)d_in[5],
        (const float*)d_in[6],  (const float*)d_in[7],
        (const float*)d_in[8],  (const float*)d_in[9],  (const float*)d_in[10],
        (const float*)d_in[11], (const float*)d_in[12], (const float*)d_in[13],
        (const float*)d_in[14], (const float*)d_in[15], (const float*)d_in[16],
        (const float*)d_in[17], (const float*)d_in[18], (const float*)d_in[19],
        (const float*)d_in[20], (const float*)d_in[21],
        W1p, (const float*)d_in[23],
        W2p, (const float*)d_in[25],
        (const float*)d_in[26], (const float*)d_in[27],
        (float*)d_out, B);
}

// Round 5
// 274.798 us; speedup vs baseline: 1.3046x; 1.0776x over previous
//
#include <hip/hip_runtime.h>

// DeepFM fused ranker, fp32.
// R9: split at the A/B boundary. Three rounds showed the fused kernel can't
// satisfy both phases: gather phase wants loads-in-flight (VGPR 200 unbounded,
// R8 -> 2 waves/SIMD, Occ 10.6%), MLP wants waves (VGPR<=64 forced -> spill
// bomb, R7). Split kernels get separate register budgets:
//  - gather_fm: 2 rows/wave, grid ceil(B/8), no LDS, ~50 VGPR -> 32 waves/CU.
//    Writes deep_in [B][200] + FM scalar rs[B] to workspace.
//  - mlp: acts read straight from global (16-lane same-addr -> 1 L2 req; no
//    staging barrier), h1 via LDS, R4's weight tiling, #pragma unroll 2 caps
//    pipelining so VGPR stays ~<=128. grid ceil(B/16) -> 4 blocks/CU.

typedef float v2f __attribute__((ext_vector_type(2)));
static __device__ __forceinline__ v2f bc2(float x) { v2f r; r.x = x; r.y = x; return r; }
static __device__ __forceinline__ float relu1(float x) { return fmaxf(x, 0.f); }

#define H1_STRIDE 132            // floats; 33 float4

// ---- pre-pass: pair-transposed packed weights (R4 layout) ----
// W1p[((wid*50+k4)*16+jp)*2+s] = {W1[j0][c],W1[j1][c],W1[j0][c+1],W1[j1][c+1]}
//   j0 = 32*wid + 2*jp, c = 4*k4 + 2*s
// W2p[((wid*32+k4)*8+jp)*2+s]  = same with j0 = 16*wid + 2*jp, row len 128
__global__ void pack_weights(const float* __restrict__ W1, const float* __restrict__ W2,
                             float4* __restrict__ W1p, float4* __restrict__ W2p) {
    const int idx = blockIdx.x * blockDim.x + threadIdx.x;
    if (idx < 6400) {
        const int s = idx & 1, jp = (idx >> 1) & 15, k4 = (idx >> 5) % 50, w = idx / 1600;
        const int j0 = w * 32 + 2 * jp, c = 4 * k4 + 2 * s;
        W1p[idx] = make_float4(W1[j0 * 200 + c],     W1[(j0 + 1) * 200 + c],
                               W1[j0 * 200 + c + 1], W1[(j0 + 1) * 200 + c + 1]);
    }
    if (idx < 2048) {
        const int s = idx & 1, jp = (idx >> 1) & 7, k4 = (idx >> 4) & 31, w = idx >> 9;
        const int j0 = w * 16 + 2 * jp, c = 4 * k4 + 2 * s;
        W2p[idx] = make_float4(W2[j0 * 128 + c],     W2[(j0 + 1) * 128 + c],
                               W2[j0 * 128 + c + 1], W2[(j0 + 1) * 128 + c + 1]);
    }
}

// ---- kernel 1: gathers + FM first/second order -> di[B][200], rs[B] ----
__global__ __launch_bounds__(256) void gather_fm_kernel(
    const int* __restrict__ user_id, const int* __restrict__ item_id,
    const int* __restrict__ gender_, const int* __restrict__ age_,
    const int* __restrict__ occ_, const int* __restrict__ genre_ids,
    const float* __restrict__ genre_mask, const float* __restrict__ dense,
    const float* __restrict__ fo_user, const float* __restrict__ fo_item,
    const float* __restrict__ fo_gender, const float* __restrict__ fo_age,
    const float* __restrict__ fo_occ, const float* __restrict__ fo_genre,
    const float* __restrict__ emb_user, const float* __restrict__ emb_item,
    const float* __restrict__ emb_gender, const float* __restrict__ emb_age,
    const float* __restrict__ emb_occ, const float* __restrict__ emb_genre,
    const float* __restrict__ dense_W, const float* __restrict__ dense_b,
    float* __restrict__ di, float* __restrict__ rs, int B)
{
    const int tid = threadIdx.x;
    const int wid = tid >> 6;
    const int lane = tid & 63;
    const int waveG = blockIdx.x * 4 + wid;
    const int d = lane & 31;

    #pragma unroll
    for (int r = 0; r < 2; ++r) {
        int row = waveG * 2 + r; if (row >= B) row = B - 1;

        // wave-uniform ids (same-address broadcast loads)
        const int uid = user_id[row], iid = item_id[row];
        const int gg = gender_[row], aa = age_[row], oo = occ_[row];

        int gid[6]; float mk[6]; float msum = 0.f;
        #pragma unroll
        for (int t = 0; t < 6; ++t) {
            gid[t] = genre_ids[row * 6 + t];
            mk[t]  = genre_mask[row * 6 + t];
            msum  += mk[t];
        }
        const float inv_den = 1.0f / fmaxf(msum, 1.0f);

        // 3 rounds of 64-lane gathers (2 fields x 32 dims each)
        const float v0 = (lane < 32) ? emb_user[(size_t)uid * 32 + d]
                                     : emb_item[(size_t)iid * 32 + d];
        const float v1 = (lane < 32) ? emb_gender[gg * 32 + d]
                                     : emb_age[aa * 32 + d];
        float v2;
        if (lane < 32) {
            v2 = emb_occ[oo * 32 + d];
        } else {
            float s = 0.f;
            #pragma unroll
            for (int t = 0; t < 6; ++t) s += mk[t] * emb_genre[gid[t] * 32 + d];
            v2 = s * inv_den;
        }

        float* __restrict__ dro = di + (size_t)row * 200;
        dro[lane] = v0;          // coalesced 64-lane stores
        dro[64 + lane] = v1;
        dro[128 + lane] = v2;
        if (lane < 8) dro[192 + lane] = dense[(size_t)row * 8 + lane];

        // FM second order: per-dim 6-field sum via the lane/lane+32 pairing
        const float pe_sum = v0 + v1 + v2;
        const float pe_sq  = v0 * v0 + v1 * v1 + v2 * v2;
        const float s2 = pe_sum + __shfl_xor(pe_sum, 32);
        const float ss = pe_sq  + __shfl_xor(pe_sq, 32);
        float t2 = 0.5f * (s2 * s2 - ss);
        #pragma unroll
        for (int off = 16; off >= 1; off >>= 1) t2 += __shfl_xor(t2, off);

        // FM first order (broadcast loads, redundant across lanes)
        float fo = fo_user[uid] + fo_item[iid] + fo_gender[gg]
                 + fo_age[aa] + fo_occ[oo];
        float fg = 0.f;
        #pragma unroll
        for (int t = 0; t < 6; ++t) fg += mk[t] * fo_genre[gid[t]];
        fo += fg * inv_den;
        float dd = 0.f;
        #pragma unroll
        for (int j = 0; j < 8; ++j) dd += dense[(size_t)row * 8 + j] * dense_W[j];
        fo += dd + dense_b[0];

        if (lane == 0) rs[row] = fo + t2;
    }
}

// ---- kernel 2: MLP. 16 rows/block, acts direct from global (L2) ----
__global__ __launch_bounds__(256) void mlp_kernel(
    const float4* __restrict__ W1p, const float* __restrict__ b1,
    const float4* __restrict__ W2p, const float* __restrict__ b2,
    const float* __restrict__ Wout, const float* __restrict__ bout,
    const float* __restrict__ di, const float* __restrict__ rs,
    float* __restrict__ out, int B)
{
    __shared__ float h1s[16][H1_STRIDE];   // 8.25 KB
    __shared__ float lds_part[16][4];

    const int tid = threadIdx.x;
    const int wid = tid >> 6;
    const int lane = tid & 63;
    const int row0 = blockIdx.x * 16;

    // ---------------- Phase B: h1 = relu(deep_in @ W1^T + b1) ------------------
    // wave owns neurons [32*wid, 32*wid+32); jp1=lane&15 -> neuron pair,
    // rh=lane>>4 -> rows {rh+4r}. Acts: 4 global b128/k4, 16-lane same-addr ->
    // 4 L2 requests/wave; weights: 2 b128/k4, 16-addr contiguous coalesced.
    const int jp1 = lane & 15;
    const int rh  = lane >> 4;

    v2f acc[4];
    #pragma unroll
    for (int r = 0; r < 4; ++r) acc[r] = bc2(0.f);

    {
        const float4* __restrict__ W1b = W1p + wid * 1600;
        const float4* __restrict__ dg = reinterpret_cast<const float4*>(di); // row stride 50

        #pragma unroll 2
        for (int k4 = 0; k4 < 50; ++k4) {
            const float4 wa = W1b[(k4 * 16 + jp1) * 2 + 0];   // {j0k0,j1k0,j0k1,j1k1}
            const float4 wb = W1b[(k4 * 16 + jp1) * 2 + 1];   // {j0k2,j1k2,j0k3,j1k3}
            const v2f w0 = { wa.x, wa.y }, w1 = { wa.z, wa.w };
            const v2f w2 = { wb.x, wb.y }, w3 = { wb.z, wb.w };
            #pragma unroll
            for (int r = 0; r < 4; ++r) {
                const float4 a = dg[(size_t)(row0 + rh + 4 * r) * 50 + k4];
                acc[r] = __builtin_elementwise_fma(w0, bc2(a.x), acc[r]);
                acc[r] = __builtin_elementwise_fma(w1, bc2(a.y), acc[r]);
                acc[r] = __builtin_elementwise_fma(w2, bc2(a.z), acc[r]);
                acc[r] = __builtin_elementwise_fma(w3, bc2(a.w), acc[r]);
            }
        }
    }

    {
        const int j0 = wid * 32 + 2 * jp1;
        const float2 bb = *reinterpret_cast<const float2*>(b1 + j0);
        #pragma unroll
        for (int r = 0; r < 4; ++r) {
            const int row = rh + 4 * r;
            *reinterpret_cast<float2*>(&h1s[row][j0]) =
                make_float2(relu1(acc[r].x + bb.x), relu1(acc[r].y + bb.y));
        }
    }
    __syncthreads();

    // ---------------- Phase C: h2 = relu(h1 @ W2^T + b2) -----------------------
    // jp2=lane&7 -> neuron pair, rh2=lane>>3 -> rows {rh2+8t}. h1 from LDS,
    // stride 132: 8 distinct rows at dword-banks {0,4,..,28} -> full cover.
    const int jp2 = lane & 7;
    const int rh2 = lane >> 3;

    v2f acc2[2];
    acc2[0] = bc2(0.f); acc2[1] = bc2(0.f);

    {
        const float4* __restrict__ W2b = W2p + wid * 512;

        #pragma unroll 2
        for (int k4 = 0; k4 < 32; ++k4) {
            const float4 wa = W2b[(k4 * 8 + jp2) * 2 + 0];
            const float4 wb = W2b[(k4 * 8 + jp2) * 2 + 1];
            const v2f w0 = { wa.x, wa.y }, w1 = { wa.z, wa.w };
            const v2f w2 = { wb.x, wb.y }, w3 = { wb.z, wb.w };
            #pragma unroll
            for (int t = 0; t < 2; ++t) {
                const float4 h = *reinterpret_cast<const float4*>(&h1s[rh2 + 8 * t][k4 * 4]);
                acc2[t] = __builtin_elementwise_fma(w0, bc2(h.x), acc2[t]);
                acc2[t] = __builtin_elementwise_fma(w1, bc2(h.y), acc2[t]);
                acc2[t] = __builtin_elementwise_fma(w2, bc2(h.z), acc2[t]);
                acc2[t] = __builtin_elementwise_fma(w3, bc2(h.w), acc2[t]);
            }
        }
    }

    // ---------------- Phase D: Wout dot + combine ------------------------------
    {
        const int j0 = wid * 16 + 2 * jp2;
        const float2 bb2 = *reinterpret_cast<const float2*>(b2 + j0);
        const float2 wo  = *reinterpret_cast<const float2*>(Wout + j0);
        #pragma unroll
        for (int t = 0; t < 2; ++t) {
            const float h2x = relu1(acc2[t].x + bb2.x);
            const float h2y = relu1(acc2[t].y + bb2.y);
            float v = wo.x * h2x + wo.y * h2y;
            v += __shfl_xor(v, 1); v += __shfl_xor(v, 2); v += __shfl_xor(v, 4);
            if (jp2 == 0) lds_part[rh2 + 8 * t][wid] = v;
        }
    }
    __syncthreads();

    if (tid < 16) {
        const int row = row0 + tid;
        if (row < B) {
            const float deep = lds_part[tid][0] + lds_part[tid][1]
                             + lds_part[tid][2] + lds_part[tid][3] + bout[0];
            out[row] = deep + rs[row];
        }
    }
}

extern "C" void kernel_launch(void* const* d_in, const int* in_sizes, int n_in,
                              void* d_out, int out_size, void* d_ws, size_t ws_size,
                              hipStream_t stream) {
    const int B = in_sizes[0];

    float4* W1p = reinterpret_cast<float4*>(d_ws);                  // 6400 float4 = 100 KB
    float4* W2p = reinterpret_cast<float4*>((char*)d_ws + 102400);  // 2048 float4 = 32 KB
    float*  di  = reinterpret_cast<float*>((char*)d_ws + 262144);   // B*200 floats
    float*  rs  = reinterpret_cast<float*>((char*)d_ws + 262144 + (size_t)B * 800);

    pack_weights<<<25, 256, 0, stream>>>(
        (const float*)d_in[22], (const float*)d_in[24], W1p, W2p);

    const int gatherBlocks = (B + 7) / 8;    // 4 waves x 2 rows = 8 rows/block
    gather_fm_kernel<<<gatherBlocks, 256, 0, stream>>>(
        (const int*)d_in[0],  (const int*)d_in[1],  (const int*)d_in[2],
        (const int*)d_in[3],  (const int*)d_in[4],  (const int*)d_in[5],
        (const float*)d_in[6],  (const float*)d_in[7],
        (const float*)d_in[8],  (const float*)d_in[9],  (const float*)d_in[10],
        (const float*)d_in[11], (const float*)d_in[12], (const float*)d_in[13],
        (const float*)d_in[14], (const float*)d_in[15], (const float*)d_in[16],
        (const float*)d_in[17], (const float*)d_in[18], (const float*)d_in[19],
        (const float*)d_in[20], (const float*)d_in[21],
        di, rs, B);

    const int mlpBlocks = (B + 15) / 16;     // 16 rows/block
    mlp_kernel<<<mlpBlocks, 256, 0, stream>>>(
        W1p, (const float*)d_in[23],
        W2p, (const float*)d_in[25],
        (const float*)d_in[26], (const float*)d_in[27],
        di, rs, (float*)d_out, B);
}